// Round 5
// baseline (242.975 us; speedup 1.0000x reference)
//
#include <hip/hip_runtime.h>
#include <hip/hip_bf16.h>
#include <cstdint>
#include <cstddef>

// ---------------------------------------------------------------------------
// MHA forward, MI355X (gfx950).  Pipeline:
//   K0a: x fp32 -> bf16                      (copy-cast, vectorized)
//   K0b: Wq/Wk/Wv/Wo fp32 -> bf16 TRANSPOSED (LDS-tiled transpose)
//   K1 : QKV = x @ [Wq|Wk|Wv]   (m97-structure bf16 MFMA GEMM, B^T input)
//         epilogue scatters Q (pre-scaled by log2e/sqrt(d)), K -> [b,h,t,d]
//         and V -> [b,h,d,t] (transposed)
//   K2 : causal flash attention  -> ctx [b,t,h*d] bf16
//        R4: K LDS-staged (dbuf+prefetch, XOR swizzle); V direct-to-register
//        fragments (loads issued at loop top, covered by QK^T+softmax);
//        defer-max (THR=8); XCD-aware remap, descending qt.
//   K3 : out = ctx @ Wo + bo     (same GEMM structure, fp32 output)
// ---------------------------------------------------------------------------

typedef __bf16 bf16_t;
typedef __bf16 bf16x8 __attribute__((ext_vector_type(8)));
typedef float  f32x4  __attribute__((ext_vector_type(4)));

#define B_SZ 2
#define T_SZ 2048
#define DIN  1024
#define NH   16
#define HD   64

// log2(e)/sqrt(HD): folded into Q at QKV-epilogue time.
#define SCL_Q (0.125f * 1.44269504088896f)

// async global->LDS, 16B per lane.  LDS dest must be wave-uniform base;
// HW adds lane*16 (learn_hip m104).  Global src IS per-lane -> swizzle there.
__device__ __forceinline__ void gld_lds16(const void* g, void* l) {
    __builtin_amdgcn_global_load_lds(
        (const __attribute__((address_space(1))) void*)g,
        (__attribute__((address_space(3))) void*)l,
        16, 0, 0);
}

// ---------------------------------------------------------------------------
// K0a: fp32 -> bf16 straight cast.  8 elems / thread.
// ---------------------------------------------------------------------------
__global__ __launch_bounds__(256) void cvt_x_kernel(const float* __restrict__ src,
                                                    bf16_t* __restrict__ dst) {
    int i = blockIdx.x * blockDim.x + threadIdx.x;
    size_t base = (size_t)i * 8;
    float4 a = *(const float4*)(src + base);
    float4 b = *(const float4*)(src + base + 4);
    bf16x8 v;
    v[0] = (bf16_t)a.x; v[1] = (bf16_t)a.y; v[2] = (bf16_t)a.z; v[3] = (bf16_t)a.w;
    v[4] = (bf16_t)b.x; v[5] = (bf16_t)b.y; v[6] = (bf16_t)b.z; v[7] = (bf16_t)b.w;
    *(bf16x8*)(dst + base) = v;
}

// ---------------------------------------------------------------------------
// K0b: src[R][C] fp32 -> dst[C][R] bf16 (transpose + cast), 32x32 LDS tiles.
// ---------------------------------------------------------------------------
__global__ __launch_bounds__(256) void transpose_cvt_kernel(const float* __restrict__ src,
                                                            bf16_t* __restrict__ dst,
                                                            int R, int C) {
    __shared__ float tile[32][33];                    // +1 pad: conflict-free
    int c0 = blockIdx.x * 32, r0 = blockIdx.y * 32;
    int tx = threadIdx.x, ty = threadIdx.y;           // 32 x 8
#pragma unroll
    for (int i = 0; i < 32; i += 8)
        tile[ty + i][tx] = src[(size_t)(r0 + ty + i) * C + c0 + tx];
    __syncthreads();
#pragma unroll
    for (int i = 0; i < 32; i += 8)
        dst[(size_t)(c0 + ty + i) * R + r0 + tx] = (bf16_t)tile[tx][ty + i];
}

// ---------------------------------------------------------------------------
// Shared GEMM tile body (m97 structure): C[128x128] += A[128xK] * Bt[128xK]^T
// A row-major [M][K], Bt row-major [N][K] (i.e. B transposed), both bf16.
// 4 waves, each owns a 64x64 quadrant = 4x4 16x16 fragments.
// ---------------------------------------------------------------------------
__device__ __forceinline__ void gemm_tile_body(const bf16_t* __restrict__ A,
                                               const bf16_t* __restrict__ Bt,
                                               int m0, int n0, int K,
                                               f32x4 acc[4][4],
                                               bf16_t* As, bf16_t* Bs) {
    const int tid  = threadIdx.x;
    const int lane = tid & 63;
    const int wave = tid >> 6;
    const int wr   = (wave >> 1) * 64;   // wave row offset in tile
    const int wc   = (wave & 1) * 64;    // wave col offset in tile

#pragma unroll
    for (int mi = 0; mi < 4; ++mi)
#pragma unroll
        for (int ni = 0; ni < 4; ++ni)
            acc[mi][ni] = (f32x4){0.f, 0.f, 0.f, 0.f};

    for (int k0 = 0; k0 < K; k0 += 32) {
        // ---- stage 128x32 A-tile and 128x32 Bt-tile (8KB each) ----
#pragma unroll
        for (int c = 0; c < 2; ++c) {
            int fb = (wave * 2 + c) * 1024;       // byte offset (wave-uniform)
            int e  = (fb >> 1) + lane * 8;        // element index of this lane
            int r  = e >> 5;                      // row (0..127)
            int kk = e & 31;                      // col (0..31)
            gld_lds16(A  + (size_t)(m0 + r) * K + k0 + kk, (char*)As + fb);
            gld_lds16(Bt + (size_t)(n0 + r) * K + k0 + kk, (char*)Bs + fb);
        }
        __syncthreads();   // drains vmcnt: LDS tiles ready

        bf16x8 af[4], bfr[4];
#pragma unroll
        for (int mi = 0; mi < 4; ++mi)
            af[mi] = *(const bf16x8*)(As + (wr + mi * 16 + (lane & 15)) * 32 + ((lane >> 4) * 8));
#pragma unroll
        for (int ni = 0; ni < 4; ++ni)
            bfr[ni] = *(const bf16x8*)(Bs + (wc + ni * 16 + (lane & 15)) * 32 + ((lane >> 4) * 8));
#pragma unroll
        for (int mi = 0; mi < 4; ++mi)
#pragma unroll
            for (int ni = 0; ni < 4; ++ni)
                acc[mi][ni] = __builtin_amdgcn_mfma_f32_16x16x32_bf16(af[mi], bfr[ni], acc[mi][ni], 0, 0, 0);
        __syncthreads();   // tile consumed; safe to overwrite
    }
}

// ---------------------------------------------------------------------------
// K1: QKV projection.  x_bf[4096][1024] @ Wqkv_t[3072][1024]^T.
// Epilogue scatters into Q[b,h,t,d] (pre-scaled), K[b,h,t,d], Vt[b,h,d,t].
// ---------------------------------------------------------------------------
__global__ __launch_bounds__(256, 2) void gemm_qkv_kernel(const bf16_t* __restrict__ A,
                                                          const bf16_t* __restrict__ Bt,
                                                          bf16_t* __restrict__ Qb,
                                                          bf16_t* __restrict__ Kb,
                                                          bf16_t* __restrict__ Vt) {
    __shared__ alignas(16) bf16_t As[128 * 32];
    __shared__ alignas(16) bf16_t Bs[128 * 32];
    const int nTn = 3072 / 128;   // 24
    int m0 = (blockIdx.x / nTn) * 128;
    int n0 = (blockIdx.x % nTn) * 128;
    f32x4 acc[4][4];
    gemm_tile_body(A, Bt, m0, n0, DIN, acc, As, Bs);

    const int lane = threadIdx.x & 63;
    const int wave = threadIdx.x >> 6;
    const int wr = (wave >> 1) * 64, wc = (wave & 1) * 64;
#pragma unroll
    for (int mi = 0; mi < 4; ++mi)
#pragma unroll
        for (int ni = 0; ni < 4; ++ni)
#pragma unroll
            for (int j = 0; j < 4; ++j) {
                int m = m0 + wr + mi * 16 + ((lane >> 4) * 4) + j;
                int n = n0 + wc + ni * 16 + (lane & 15);
                int b = m >> 11, t = m & 2047;
                int part = n >> 10, c = n & 1023;
                int h = c >> 6, d = c & 63;
                float av = acc[mi][ni][j];
                if (part == 0)
                    Qb[(((size_t)(b * NH + h) * T_SZ + t) << 6) + d] = (bf16_t)(av * SCL_Q);
                else if (part == 1)
                    Kb[(((size_t)(b * NH + h) * T_SZ + t) << 6) + d] = (bf16_t)av;
                else
                    Vt[((size_t)(b * NH + h) * HD + d) * T_SZ + t] = (bf16_t)av;
            }
}

// ---------------------------------------------------------------------------
// K2: causal flash attention.  Block = 64 Q-rows of one (b,h); 4 waves x 16
// rows.  K tiles LDS-staged (dbuf, prefetch, XOR swizzle via pre-swizzled
// global source — rule #21).  V fragments loaded straight into registers at
// loop top (contiguous in Vt[d][t] layout); covered by QK^T + softmax.
// Defer-max: skip O-rescale while tile max stays within THR of running max.
// Block remap: 4 heads per XCD (L2-resident K/V), descending qt (balance).
// ---------------------------------------------------------------------------
__global__ __launch_bounds__(256, 3) void attn_kernel(const bf16_t* __restrict__ Qb,
                                                      const bf16_t* __restrict__ Kb,
                                                      const bf16_t* __restrict__ Vt,
                                                      bf16_t* __restrict__ ctx) {
    __shared__ alignas(16) bf16_t Ks[2][64 * 64];     // [buf][row*64 + col]
    __shared__ alignas(16) bf16_t P_lds[4][16][72];   // per-wave P tile, +8 pad

    const int raw = blockIdx.x;         // 0..1023
    const int xcd = raw & 7;            // heuristic XCD id (dispatch i%8)
    const int jj  = raw >> 3;           // 0..127
    const int bh  = xcd * 4 + (jj & 3); // 4 heads per XCD -> 2MB K/V in L2
    const int qt  = 31 - (jj >> 2);     // big tiles dispatch first

    const int lane = threadIdx.x & 63;
    const int wave = threadIdx.x >> 6;

    const bf16_t* Qp = Qb + (size_t)bh * T_SZ * HD;
    const bf16_t* Kp = Kb + (size_t)bh * T_SZ * HD;
    const bf16_t* Vp = Vt + (size_t)bh * HD * T_SZ;

    const int q0 = qt * 64 + wave * 16;      // this wave's first q row
    const int rgrp = lane >> 4;              // 0..3
    const int rcol = lane & 15;              // 0..15

    // staging: each wave 2 calls/tile; call covers 8 rows (64 lanes x 16B).
    // lane l -> row r = r0 + (l>>3), LDS slot l&7; global slot = (l&7)^(r&7).
    const int st_r  = (lane >> 3);           // 0..7 within 8-row chunk
    const int st_sl = lane & 7;

    // Q fragments for 16 rows (A-operand: row=lane&15, k=8*(lane>>4)+i)
    bf16x8 qa[2];
#pragma unroll
    for (int s = 0; s < 2; ++s)
        qa[s] = *(const bf16x8*)(Qp + (size_t)(q0 + rcol) * HD + s * 32 + rgrp * 8);

    f32x4 o[4];
#pragma unroll
    for (int di = 0; di < 4; ++di) o[di] = (f32x4){0.f, 0.f, 0.f, 0.f};
    float mrun[4], lrun[4];
#pragma unroll
    for (int j = 0; j < 4; ++j) { mrun[j] = -__builtin_inff(); lrun[j] = 0.f; }

#define STAGE_K(BUF, KT)                                                        \
    {                                                                           \
        const int k0s = (KT) * 64;                                              \
        _Pragma("unroll")                                                       \
        for (int c = 0; c < 2; ++c) {                                           \
            int r0 = (wave * 2 + c) * 8;                                        \
            int r  = r0 + st_r;                                                 \
            int sl = st_sl ^ (r & 7);                                           \
            gld_lds16(Kp + (size_t)(k0s + r) * HD + sl * 8,                     \
                      (char*)&Ks[BUF][0] + r0 * 128);                           \
        }                                                                       \
    }

    STAGE_K(0, 0);
    __syncthreads();                 // drains vmcnt: buf0 ready
    int buf = 0;

    for (int kt = 0; kt <= qt; ++kt) {
        const int k0 = kt * 64;
        if (kt < qt) STAGE_K(buf ^ 1, kt + 1);   // prefetch next K tile

        // ---- V fragments for THIS tile: direct global -> regs (B-frag
        // layout is contiguous in Vt[d][t]); lands during QK^T+softmax ----
        bf16x8 vf[2][4];
#pragma unroll
        for (int s = 0; s < 2; ++s)
#pragma unroll
            for (int di = 0; di < 4; ++di)
                vf[s][di] = *(const bf16x8*)(Vp + (size_t)(di * 16 + rcol) * T_SZ + k0 + s * 32 + rgrp * 8);

        const char* Kb_l = (const char*)&Ks[buf][0];

        // ---- S = Q K^T  (4 col-tiles x 2 k-steps); Q pre-scaled ----
        f32x4 s_acc[4];
#pragma unroll
        for (int ni = 0; ni < 4; ++ni) s_acc[ni] = (f32x4){0.f, 0.f, 0.f, 0.f};
#pragma unroll
        for (int s = 0; s < 2; ++s)
#pragma unroll
            for (int ni = 0; ni < 4; ++ni) {
                int fr = ni * 16 + rcol;
                bf16x8 kb = *(const bf16x8*)(Kb_l + fr * 128 + (((s * 4 + rgrp) ^ (fr & 7)) << 4));
                s_acc[ni] = __builtin_amdgcn_mfma_f32_16x16x32_bf16(qa[s], kb, s_acc[ni], 0, 0, 0);
            }

        // ---- tile max (+ causal mask on diagonal tile); log2 units ----
        float ptile[4][4];                       // [ni][j]
        float mt[4];
#pragma unroll
        for (int j = 0; j < 4; ++j) mt[j] = -__builtin_inff();
        if (kt == qt) {                          // diagonal: apply causal mask
#pragma unroll
            for (int ni = 0; ni < 4; ++ni)
#pragma unroll
                for (int j = 0; j < 4; ++j) {
                    int q = q0 + rgrp * 4 + j;
                    int kidx = qt * 64 + ni * 16 + rcol;
                    float v = s_acc[ni][j];
                    if (kidx > q) v = -__builtin_inff();
                    ptile[ni][j] = v;
                    mt[j] = fmaxf(mt[j], v);
                }
        } else {
#pragma unroll
            for (int ni = 0; ni < 4; ++ni)
#pragma unroll
                for (int j = 0; j < 4; ++j) {
                    float v = s_acc[ni][j];
                    ptile[ni][j] = v;
                    mt[j] = fmaxf(mt[j], v);
                }
        }
#pragma unroll
        for (int j = 0; j < 4; ++j) {            // row-max across 16 lanes
            float m = mt[j];
            m = fmaxf(m, __shfl_xor(m, 1));
            m = fmaxf(m, __shfl_xor(m, 2));
            m = fmaxf(m, __shfl_xor(m, 4));
            m = fmaxf(m, __shfl_xor(m, 8));
            mt[j] = m;
        }
        // ---- defer-max (T13, THR=8 in log2 units): skip rescale while the
        // tile max stays within THR of the running max (wave-uniform) ----
        bool need = false;
#pragma unroll
        for (int j = 0; j < 4; ++j) need |= (mt[j] > mrun[j] + 8.f);
        const bool full = !__all(!need);
        float alpha[4];
        if (full) {
#pragma unroll
            for (int j = 0; j < 4; ++j) {
                float newm = fmaxf(mrun[j], mt[j]);
                alpha[j] = exp2f(mrun[j] - newm);   // exp2(-inf)=0 first tile
                mrun[j] = newm;
            }
        }
        float rsum[4];
#pragma unroll
        for (int j = 0; j < 4; ++j) rsum[j] = 0.f;
#pragma unroll
        for (int ni = 0; ni < 4; ++ni)
#pragma unroll
            for (int j = 0; j < 4; ++j) {
                float p = exp2f(ptile[ni][j] - mrun[j]);   // masked -> 0
                ptile[ni][j] = p;
                rsum[j] += p;
            }
#pragma unroll
        for (int j = 0; j < 4; ++j) {
            float r = rsum[j];
            r += __shfl_xor(r, 1);
            r += __shfl_xor(r, 2);
            r += __shfl_xor(r, 4);
            r += __shfl_xor(r, 8);
            rsum[j] = r;
        }
        if (full) {
#pragma unroll
            for (int j = 0; j < 4; ++j) lrun[j] = lrun[j] * alpha[j] + rsum[j];
#pragma unroll
            for (int di = 0; di < 4; ++di)
#pragma unroll
                for (int j = 0; j < 4; ++j)
                    o[di][j] *= alpha[j];
        } else {
#pragma unroll
            for (int j = 0; j < 4; ++j) lrun[j] += rsum[j];
        }
        // ---- P -> per-wave LDS (C-layout write), re-read as A-fragment ----
        // same-wave LDS ops are ordered; no barrier needed here.
#pragma unroll
        for (int ni = 0; ni < 4; ++ni)
#pragma unroll
            for (int j = 0; j < 4; ++j)
                P_lds[wave][rgrp * 4 + j][ni * 16 + rcol] = (bf16_t)ptile[ni][j];
        // ---- O += P V  (V already in registers) ----
#pragma unroll
        for (int s = 0; s < 2; ++s) {
            bf16x8 pa = *(const bf16x8*)(&P_lds[wave][rcol][s * 32 + rgrp * 8]);
#pragma unroll
            for (int di = 0; di < 4; ++di)
                o[di] = __builtin_amdgcn_mfma_f32_16x16x32_bf16(pa, vf[s][di], o[di], 0, 0, 0);
        }
        __syncthreads();   // K prefetch landed (vmcnt) + all waves done w/ buf
        buf ^= 1;
    }
#undef STAGE_K

    // ---- epilogue: ctx[b, t, h*64+d] = o / l ----
    const int b = bh >> 4, h = bh & 15;
    float invl[4];
#pragma unroll
    for (int j = 0; j < 4; ++j) invl[j] = 1.f / lrun[j];
#pragma unroll
    for (int di = 0; di < 4; ++di)
#pragma unroll
        for (int j = 0; j < 4; ++j) {
            int q = q0 + rgrp * 4 + j;
            int d = di * 16 + rcol;
            ctx[((size_t)(b * T_SZ + q) * NH + h) * HD + d] = (bf16_t)(o[di][j] * invl[j]);
        }
}

// ---------------------------------------------------------------------------
// K3: out = ctx @ Wo + bo   (fp32 output)
// ---------------------------------------------------------------------------
__global__ __launch_bounds__(256, 2) void gemm_out_kernel(const bf16_t* __restrict__ A,
                                                          const bf16_t* __restrict__ Bt,
                                                          const float* __restrict__ bias,
                                                          float* __restrict__ out) {
    __shared__ alignas(16) bf16_t As[128 * 32];
    __shared__ alignas(16) bf16_t Bs[128 * 32];
    const int nTn = 1024 / 128;   // 8
    int m0 = (blockIdx.x / nTn) * 128;
    int n0 = (blockIdx.x % nTn) * 128;
    f32x4 acc[4][4];
    gemm_tile_body(A, Bt, m0, n0, DIN, acc, As, Bs);

    const int lane = threadIdx.x & 63;
    const int wave = threadIdx.x >> 6;
    const int wr = (wave >> 1) * 64, wc = (wave & 1) * 64;
#pragma unroll
    for (int mi = 0; mi < 4; ++mi)
#pragma unroll
        for (int ni = 0; ni < 4; ++ni) {
            int n = n0 + wc + ni * 16 + (lane & 15);
            float bv = bias[n];
#pragma unroll
            for (int j = 0; j < 4; ++j) {
                int m = m0 + wr + mi * 16 + ((lane >> 4) * 4) + j;
                out[(size_t)m * 1024 + n] = acc[mi][ni][j] + bv;
            }
        }
}

// ---------------------------------------------------------------------------
// Launch.  Workspace layout (48 MB total):
//   [0,8M)   x_bf      [16M,24M) Qb       [32M,40M) Vt
//   [8M,14M) Wqkv_t    [24M,32M) Kb       [40M,48M) ctx
//   [14M,16M) Wo_t
// ---------------------------------------------------------------------------
extern "C" void kernel_launch(void* const* d_in, const int* in_sizes, int n_in,
                              void* d_out, int out_size, void* d_ws, size_t ws_size,
                              hipStream_t stream) {
    const float* x  = (const float*)d_in[0];
    const float* Wq = (const float*)d_in[1];
    const float* Wk = (const float*)d_in[2];
    const float* Wv = (const float*)d_in[3];
    const float* Wo = (const float*)d_in[4];
    const float* bo = (const float*)d_in[5];
    float* out = (float*)d_out;

    char* ws = (char*)d_ws;
    bf16_t* x_bf   = (bf16_t*)(ws);
    bf16_t* Wqkv_t = (bf16_t*)(ws + ((size_t)8 << 20));
    bf16_t* Wo_t   = (bf16_t*)(ws + ((size_t)14 << 20));
    bf16_t* Qb     = (bf16_t*)(ws + ((size_t)16 << 20));
    bf16_t* Kb     = (bf16_t*)(ws + ((size_t)24 << 20));
    bf16_t* Vt     = (bf16_t*)(ws + ((size_t)32 << 20));
    bf16_t* ctx    = (bf16_t*)(ws + ((size_t)40 << 20));

    // K0a: x -> bf16 (4096*1024 elems, 8/thread)
    cvt_x_kernel<<<2048, 256, 0, stream>>>(x, x_bf);
    // K0b: weight transposes ([K][N] fp32 -> [N][K] bf16)
    transpose_cvt_kernel<<<dim3(32, 32), dim3(32, 8), 0, stream>>>(Wq, Wqkv_t, 1024, 1024);
    transpose_cvt_kernel<<<dim3(32, 32), dim3(32, 8), 0, stream>>>(Wk, Wqkv_t + (size_t)1024 * 1024, 1024, 1024);
    transpose_cvt_kernel<<<dim3(32, 32), dim3(32, 8), 0, stream>>>(Wv, Wqkv_t + (size_t)2048 * 1024, 1024, 1024);
    transpose_cvt_kernel<<<dim3(32, 32), dim3(32, 8), 0, stream>>>(Wo, Wo_t, 1024, 1024);
    // K1: QKV projection (M=4096, N=3072, K=1024)
    gemm_qkv_kernel<<<32 * 24, 256, 0, stream>>>(x_bf, Wqkv_t, Qb, Kb, Vt);
    // K2: causal attention (2*16 heads * 32 q-tiles), XCD-aware remap inside
    attn_kernel<<<B_SZ * NH * 32, 256, 0, stream>>>(Qb, Kb, Vt, ctx);
    // K3: output projection (M=4096, N=1024, K=1024)
    gemm_out_kernel<<<32 * 8, 256, 0, stream>>>(ctx, Wo_t, bo, out);
}

// Round 6
// 216.875 us; speedup vs baseline: 1.1203x; 1.1203x over previous
//
#include <hip/hip_runtime.h>
#include <hip/hip_bf16.h>
#include <cstdint>
#include <cstddef>

// ---------------------------------------------------------------------------
// MHA forward, MI355X (gfx950).  Pipeline:
//   K0a: x fp32 -> bf16                      (copy-cast, vectorized)
//   K0b: Wq/Wk/Wv/Wo fp32 -> bf16 TRANSPOSED (LDS-tiled transpose)
//   K1 : QKV = x @ [Wq|Wk|Wv]   (m97-structure bf16 MFMA GEMM, B^T input)
//         epilogue scatters Q (pre-scaled by log2e/sqrt(d)), K -> [b,h,t,d]
//         and V -> [b,h,d,t] (transposed)
//   K2 : causal flash attention  -> ctx [b,t,h*d] bf16
//        R6 = R4 structure (K AND V LDS-staged, dbuf+prefetch, XOR swizzle;
//        V reg-loads reverted: block-shared data must be staged once, not
//        loaded 4x/wave with exposed latency) + kept R5 wins: pre-scaled Q,
//        defer-max (THR=8).  XCD-aware remap, descending qt.
//   K3 : out = ctx @ Wo + bo     (same GEMM structure, fp32 output)
// ---------------------------------------------------------------------------

typedef __bf16 bf16_t;
typedef __bf16 bf16x8 __attribute__((ext_vector_type(8)));
typedef float  f32x4  __attribute__((ext_vector_type(4)));

#define B_SZ 2
#define T_SZ 2048
#define DIN  1024
#define NH   16
#define HD   64

// log2(e)/sqrt(HD): folded into Q at QKV-epilogue time.
#define SCL_Q (0.125f * 1.44269504088896f)

// async global->LDS, 16B per lane.  LDS dest must be wave-uniform base;
// HW adds lane*16 (learn_hip m104).  Global src IS per-lane -> swizzle there.
__device__ __forceinline__ void gld_lds16(const void* g, void* l) {
    __builtin_amdgcn_global_load_lds(
        (const __attribute__((address_space(1))) void*)g,
        (__attribute__((address_space(3))) void*)l,
        16, 0, 0);
}

// ---------------------------------------------------------------------------
// K0a: fp32 -> bf16 straight cast.  8 elems / thread.
// ---------------------------------------------------------------------------
__global__ __launch_bounds__(256) void cvt_x_kernel(const float* __restrict__ src,
                                                    bf16_t* __restrict__ dst) {
    int i = blockIdx.x * blockDim.x + threadIdx.x;
    size_t base = (size_t)i * 8;
    float4 a = *(const float4*)(src + base);
    float4 b = *(const float4*)(src + base + 4);
    bf16x8 v;
    v[0] = (bf16_t)a.x; v[1] = (bf16_t)a.y; v[2] = (bf16_t)a.z; v[3] = (bf16_t)a.w;
    v[4] = (bf16_t)b.x; v[5] = (bf16_t)b.y; v[6] = (bf16_t)b.z; v[7] = (bf16_t)b.w;
    *(bf16x8*)(dst + base) = v;
}

// ---------------------------------------------------------------------------
// K0b: src[R][C] fp32 -> dst[C][R] bf16 (transpose + cast), 32x32 LDS tiles.
// ---------------------------------------------------------------------------
__global__ __launch_bounds__(256) void transpose_cvt_kernel(const float* __restrict__ src,
                                                            bf16_t* __restrict__ dst,
                                                            int R, int C) {
    __shared__ float tile[32][33];                    // +1 pad: conflict-free
    int c0 = blockIdx.x * 32, r0 = blockIdx.y * 32;
    int tx = threadIdx.x, ty = threadIdx.y;           // 32 x 8
#pragma unroll
    for (int i = 0; i < 32; i += 8)
        tile[ty + i][tx] = src[(size_t)(r0 + ty + i) * C + c0 + tx];
    __syncthreads();
#pragma unroll
    for (int i = 0; i < 32; i += 8)
        dst[(size_t)(c0 + ty + i) * R + r0 + tx] = (bf16_t)tile[tx][ty + i];
}

// ---------------------------------------------------------------------------
// Shared GEMM tile body (m97 structure): C[128x128] += A[128xK] * Bt[128xK]^T
// A row-major [M][K], Bt row-major [N][K] (i.e. B transposed), both bf16.
// 4 waves, each owns a 64x64 quadrant = 4x4 16x16 fragments.
// ---------------------------------------------------------------------------
__device__ __forceinline__ void gemm_tile_body(const bf16_t* __restrict__ A,
                                               const bf16_t* __restrict__ Bt,
                                               int m0, int n0, int K,
                                               f32x4 acc[4][4],
                                               bf16_t* As, bf16_t* Bs) {
    const int tid  = threadIdx.x;
    const int lane = tid & 63;
    const int wave = tid >> 6;
    const int wr   = (wave >> 1) * 64;   // wave row offset in tile
    const int wc   = (wave & 1) * 64;    // wave col offset in tile

#pragma unroll
    for (int mi = 0; mi < 4; ++mi)
#pragma unroll
        for (int ni = 0; ni < 4; ++ni)
            acc[mi][ni] = (f32x4){0.f, 0.f, 0.f, 0.f};

    for (int k0 = 0; k0 < K; k0 += 32) {
        // ---- stage 128x32 A-tile and 128x32 Bt-tile (8KB each) ----
#pragma unroll
        for (int c = 0; c < 2; ++c) {
            int fb = (wave * 2 + c) * 1024;       // byte offset (wave-uniform)
            int e  = (fb >> 1) + lane * 8;        // element index of this lane
            int r  = e >> 5;                      // row (0..127)
            int kk = e & 31;                      // col (0..31)
            gld_lds16(A  + (size_t)(m0 + r) * K + k0 + kk, (char*)As + fb);
            gld_lds16(Bt + (size_t)(n0 + r) * K + k0 + kk, (char*)Bs + fb);
        }
        __syncthreads();   // drains vmcnt: LDS tiles ready

        bf16x8 af[4], bfr[4];
#pragma unroll
        for (int mi = 0; mi < 4; ++mi)
            af[mi] = *(const bf16x8*)(As + (wr + mi * 16 + (lane & 15)) * 32 + ((lane >> 4) * 8));
#pragma unroll
        for (int ni = 0; ni < 4; ++ni)
            bfr[ni] = *(const bf16x8*)(Bs + (wc + ni * 16 + (lane & 15)) * 32 + ((lane >> 4) * 8));
#pragma unroll
        for (int mi = 0; mi < 4; ++mi)
#pragma unroll
            for (int ni = 0; ni < 4; ++ni)
                acc[mi][ni] = __builtin_amdgcn_mfma_f32_16x16x32_bf16(af[mi], bfr[ni], acc[mi][ni], 0, 0, 0);
        __syncthreads();   // tile consumed; safe to overwrite
    }
}

// ---------------------------------------------------------------------------
// K1: QKV projection.  x_bf[4096][1024] @ Wqkv_t[3072][1024]^T.
// Epilogue scatters into Q[b,h,t,d] (pre-scaled), K[b,h,t,d], Vt[b,h,d,t].
// ---------------------------------------------------------------------------
__global__ __launch_bounds__(256, 2) void gemm_qkv_kernel(const bf16_t* __restrict__ A,
                                                          const bf16_t* __restrict__ Bt,
                                                          bf16_t* __restrict__ Qb,
                                                          bf16_t* __restrict__ Kb,
                                                          bf16_t* __restrict__ Vt) {
    __shared__ alignas(16) bf16_t As[128 * 32];
    __shared__ alignas(16) bf16_t Bs[128 * 32];
    const int nTn = 3072 / 128;   // 24
    int m0 = (blockIdx.x / nTn) * 128;
    int n0 = (blockIdx.x % nTn) * 128;
    f32x4 acc[4][4];
    gemm_tile_body(A, Bt, m0, n0, DIN, acc, As, Bs);

    const int lane = threadIdx.x & 63;
    const int wave = threadIdx.x >> 6;
    const int wr = (wave >> 1) * 64, wc = (wave & 1) * 64;
#pragma unroll
    for (int mi = 0; mi < 4; ++mi)
#pragma unroll
        for (int ni = 0; ni < 4; ++ni)
#pragma unroll
            for (int j = 0; j < 4; ++j) {
                int m = m0 + wr + mi * 16 + ((lane >> 4) * 4) + j;
                int n = n0 + wc + ni * 16 + (lane & 15);
                int b = m >> 11, t = m & 2047;
                int part = n >> 10, c = n & 1023;
                int h = c >> 6, d = c & 63;
                float av = acc[mi][ni][j];
                if (part == 0)
                    Qb[(((size_t)(b * NH + h) * T_SZ + t) << 6) + d] = (bf16_t)(av * SCL_Q);
                else if (part == 1)
                    Kb[(((size_t)(b * NH + h) * T_SZ + t) << 6) + d] = (bf16_t)av;
                else
                    Vt[((size_t)(b * NH + h) * HD + d) * T_SZ + t] = (bf16_t)av;
            }
}

// ---------------------------------------------------------------------------
// K2: causal flash attention.  Block = 64 Q-rows of one (b,h); 4 waves x 16
// rows.  K and V tiles (64x64 each) LDS-staged, double-buffered, prefetched
// one iteration ahead (block-shared data: stage once, read 4x from LDS).
// XOR swizzle via pre-swizzled global source + swizzled ds_read (rule #21).
// Q pre-scaled (log2 units).  Defer-max (T13, THR=8): skip O-rescale while
// tile max stays within THR of running max.
// Block remap: 4 heads per XCD (L2-resident K/V), descending qt (balance).
// ---------------------------------------------------------------------------
__global__ __launch_bounds__(256, 2) void attn_kernel(const bf16_t* __restrict__ Qb,
                                                      const bf16_t* __restrict__ Kb,
                                                      const bf16_t* __restrict__ Vt,
                                                      bf16_t* __restrict__ ctx) {
    __shared__ alignas(16) bf16_t Ks[2][64 * 64];     // [buf][row*64 + col]
    __shared__ alignas(16) bf16_t Vs[2][64 * 64];     // rows are d, cols are k
    __shared__ alignas(16) bf16_t P_lds[4][16][72];   // per-wave P tile, +8 pad

    const int raw = blockIdx.x;         // 0..1023
    const int xcd = raw & 7;            // heuristic XCD id (dispatch i%8)
    const int jj  = raw >> 3;           // 0..127
    const int bh  = xcd * 4 + (jj & 3); // 4 heads per XCD -> 2MB K/V in L2
    const int qt  = 31 - (jj >> 2);     // big tiles dispatch first

    const int lane = threadIdx.x & 63;
    const int wave = threadIdx.x >> 6;

    const bf16_t* Qp = Qb + (size_t)bh * T_SZ * HD;
    const bf16_t* Kp = Kb + (size_t)bh * T_SZ * HD;
    const bf16_t* Vp = Vt + (size_t)bh * HD * T_SZ;

    const int q0 = qt * 64 + wave * 16;      // this wave's first q row
    const int rgrp = lane >> 4;              // 0..3
    const int rcol = lane & 15;              // 0..15

    // staging: each wave 2 calls/tile; call covers 8 rows (64 lanes x 16B).
    // lane l -> row r = r0 + (l>>3), LDS slot l&7; global slot = (l&7)^(r&7).
    const int st_r  = (lane >> 3);           // 0..7 within 8-row chunk
    const int st_sl = lane & 7;

    // Q fragments for 16 rows (A-operand: row=lane&15, k=8*(lane>>4)+i)
    bf16x8 qa[2];
#pragma unroll
    for (int s = 0; s < 2; ++s)
        qa[s] = *(const bf16x8*)(Qp + (size_t)(q0 + rcol) * HD + s * 32 + rgrp * 8);

    f32x4 o[4];
#pragma unroll
    for (int di = 0; di < 4; ++di) o[di] = (f32x4){0.f, 0.f, 0.f, 0.f};
    float mrun[4], lrun[4];
#pragma unroll
    for (int j = 0; j < 4; ++j) { mrun[j] = -__builtin_inff(); lrun[j] = 0.f; }

#define STAGE(BUF, KT)                                                          \
    {                                                                           \
        const int k0s = (KT) * 64;                                              \
        _Pragma("unroll")                                                       \
        for (int c = 0; c < 2; ++c) {                                           \
            int r0 = (wave * 2 + c) * 8;                                        \
            int r  = r0 + st_r;                                                 \
            int sl = st_sl ^ (r & 7);                                           \
            gld_lds16(Kp + (size_t)(k0s + r) * HD + sl * 8,                     \
                      (char*)&Ks[BUF][0] + r0 * 128);                           \
            gld_lds16(Vp + (size_t)r * T_SZ + k0s + sl * 8,                     \
                      (char*)&Vs[BUF][0] + r0 * 128);                           \
        }                                                                       \
    }

    STAGE(0, 0);
    __syncthreads();                 // drains vmcnt: buf0 ready
    int buf = 0;

    for (int kt = 0; kt <= qt; ++kt) {
        if (kt < qt) STAGE(buf ^ 1, kt + 1);   // prefetch next tile

        const char* Kb_l = (const char*)&Ks[buf][0];
        const char* Vb_l = (const char*)&Vs[buf][0];

        // ---- S = Q K^T  (4 col-tiles x 2 k-steps); Q pre-scaled ----
        f32x4 s_acc[4];
#pragma unroll
        for (int ni = 0; ni < 4; ++ni) s_acc[ni] = (f32x4){0.f, 0.f, 0.f, 0.f};
#pragma unroll
        for (int s = 0; s < 2; ++s)
#pragma unroll
            for (int ni = 0; ni < 4; ++ni) {
                int fr = ni * 16 + rcol;
                bf16x8 kb = *(const bf16x8*)(Kb_l + fr * 128 + (((s * 4 + rgrp) ^ (fr & 7)) << 4));
                s_acc[ni] = __builtin_amdgcn_mfma_f32_16x16x32_bf16(qa[s], kb, s_acc[ni], 0, 0, 0);
            }

        // ---- tile max (+ causal mask on diagonal tile); log2 units ----
        float ptile[4][4];                       // [ni][j]
        float mt[4];
#pragma unroll
        for (int j = 0; j < 4; ++j) mt[j] = -__builtin_inff();
        if (kt == qt) {                          // diagonal: apply causal mask
#pragma unroll
            for (int ni = 0; ni < 4; ++ni)
#pragma unroll
                for (int j = 0; j < 4; ++j) {
                    int q = q0 + rgrp * 4 + j;
                    int kidx = qt * 64 + ni * 16 + rcol;
                    float v = s_acc[ni][j];
                    if (kidx > q) v = -__builtin_inff();
                    ptile[ni][j] = v;
                    mt[j] = fmaxf(mt[j], v);
                }
        } else {
#pragma unroll
            for (int ni = 0; ni < 4; ++ni)
#pragma unroll
                for (int j = 0; j < 4; ++j) {
                    float v = s_acc[ni][j];
                    ptile[ni][j] = v;
                    mt[j] = fmaxf(mt[j], v);
                }
        }
#pragma unroll
        for (int j = 0; j < 4; ++j) {            // row-max across 16 lanes
            float m = mt[j];
            m = fmaxf(m, __shfl_xor(m, 1));
            m = fmaxf(m, __shfl_xor(m, 2));
            m = fmaxf(m, __shfl_xor(m, 4));
            m = fmaxf(m, __shfl_xor(m, 8));
            mt[j] = m;
        }
        // ---- defer-max (T13, THR=8 in log2 units): skip rescale while the
        // tile max stays within THR of the running max (wave-uniform) ----
        bool need = false;
#pragma unroll
        for (int j = 0; j < 4; ++j) need |= (mt[j] > mrun[j] + 8.f);
        const bool full = !__all(!need);
        float alpha[4];
        if (full) {
#pragma unroll
            for (int j = 0; j < 4; ++j) {
                float newm = fmaxf(mrun[j], mt[j]);
                alpha[j] = exp2f(mrun[j] - newm);   // exp2(-inf)=0 first tile
                mrun[j] = newm;
            }
        }
        float rsum[4];
#pragma unroll
        for (int j = 0; j < 4; ++j) rsum[j] = 0.f;
#pragma unroll
        for (int ni = 0; ni < 4; ++ni)
#pragma unroll
            for (int j = 0; j < 4; ++j) {
                float p = exp2f(ptile[ni][j] - mrun[j]);   // masked -> 0
                ptile[ni][j] = p;
                rsum[j] += p;
            }
#pragma unroll
        for (int j = 0; j < 4; ++j) {
            float r = rsum[j];
            r += __shfl_xor(r, 1);
            r += __shfl_xor(r, 2);
            r += __shfl_xor(r, 4);
            r += __shfl_xor(r, 8);
            rsum[j] = r;
        }
        if (full) {
#pragma unroll
            for (int j = 0; j < 4; ++j) lrun[j] = lrun[j] * alpha[j] + rsum[j];
#pragma unroll
            for (int di = 0; di < 4; ++di)
#pragma unroll
                for (int j = 0; j < 4; ++j)
                    o[di][j] *= alpha[j];
        } else {
#pragma unroll
            for (int j = 0; j < 4; ++j) lrun[j] += rsum[j];
        }
        // ---- P -> per-wave LDS (C-layout write), re-read as A-fragment ----
        // same-wave LDS ops are ordered; no barrier needed here.
#pragma unroll
        for (int ni = 0; ni < 4; ++ni)
#pragma unroll
            for (int j = 0; j < 4; ++j)
                P_lds[wave][rgrp * 4 + j][ni * 16 + rcol] = (bf16_t)ptile[ni][j];
        // ---- O += P V  (V from LDS, swizzled read) ----
#pragma unroll
        for (int s = 0; s < 2; ++s) {
            bf16x8 pa = *(const bf16x8*)(&P_lds[wave][rcol][s * 32 + rgrp * 8]);
#pragma unroll
            for (int di = 0; di < 4; ++di) {
                int fv = di * 16 + rcol;
                bf16x8 vb = *(const bf16x8*)(Vb_l + fv * 128 + (((s * 4 + rgrp) ^ (fv & 7)) << 4));
                o[di] = __builtin_amdgcn_mfma_f32_16x16x32_bf16(pa, vb, o[di], 0, 0, 0);
            }
        }
        __syncthreads();   // prefetch landed (vmcnt) + all waves done with buf
        buf ^= 1;
    }
#undef STAGE

    // ---- epilogue: ctx[b, t, h*64+d] = o / l ----
    const int b = bh >> 4, h = bh & 15;
    float invl[4];
#pragma unroll
    for (int j = 0; j < 4; ++j) invl[j] = 1.f / lrun[j];
#pragma unroll
    for (int di = 0; di < 4; ++di)
#pragma unroll
        for (int j = 0; j < 4; ++j) {
            int q = q0 + rgrp * 4 + j;
            int d = di * 16 + rcol;
            ctx[((size_t)(b * T_SZ + q) * NH + h) * HD + d] = (bf16_t)(o[di][j] * invl[j]);
        }
}

// ---------------------------------------------------------------------------
// K3: out = ctx @ Wo + bo   (fp32 output)
// ---------------------------------------------------------------------------
__global__ __launch_bounds__(256, 2) void gemm_out_kernel(const bf16_t* __restrict__ A,
                                                          const bf16_t* __restrict__ Bt,
                                                          const float* __restrict__ bias,
                                                          float* __restrict__ out) {
    __shared__ alignas(16) bf16_t As[128 * 32];
    __shared__ alignas(16) bf16_t Bs[128 * 32];
    const int nTn = 1024 / 128;   // 8
    int m0 = (blockIdx.x / nTn) * 128;
    int n0 = (blockIdx.x % nTn) * 128;
    f32x4 acc[4][4];
    gemm_tile_body(A, Bt, m0, n0, DIN, acc, As, Bs);

    const int lane = threadIdx.x & 63;
    const int wave = threadIdx.x >> 6;
    const int wr = (wave >> 1) * 64, wc = (wave & 1) * 64;
#pragma unroll
    for (int mi = 0; mi < 4; ++mi)
#pragma unroll
        for (int ni = 0; ni < 4; ++ni) {
            int n = n0 + wc + ni * 16 + (lane & 15);
            float bv = bias[n];
#pragma unroll
            for (int j = 0; j < 4; ++j) {
                int m = m0 + wr + mi * 16 + ((lane >> 4) * 4) + j;
                out[(size_t)m * 1024 + n] = acc[mi][ni][j] + bv;
            }
        }
}

// ---------------------------------------------------------------------------
// Launch.  Workspace layout (48 MB total):
//   [0,8M)   x_bf      [16M,24M) Qb       [32M,40M) Vt
//   [8M,14M) Wqkv_t    [24M,32M) Kb       [40M,48M) ctx
//   [14M,16M) Wo_t
// ---------------------------------------------------------------------------
extern "C" void kernel_launch(void* const* d_in, const int* in_sizes, int n_in,
                              void* d_out, int out_size, void* d_ws, size_t ws_size,
                              hipStream_t stream) {
    const float* x  = (const float*)d_in[0];
    const float* Wq = (const float*)d_in[1];
    const float* Wk = (const float*)d_in[2];
    const float* Wv = (const float*)d_in[3];
    const float* Wo = (const float*)d_in[4];
    const float* bo = (const float*)d_in[5];
    float* out = (float*)d_out;

    char* ws = (char*)d_ws;
    bf16_t* x_bf   = (bf16_t*)(ws);
    bf16_t* Wqkv_t = (bf16_t*)(ws + ((size_t)8 << 20));
    bf16_t* Wo_t   = (bf16_t*)(ws + ((size_t)14 << 20));
    bf16_t* Qb     = (bf16_t*)(ws + ((size_t)16 << 20));
    bf16_t* Kb     = (bf16_t*)(ws + ((size_t)24 << 20));
    bf16_t* Vt     = (bf16_t*)(ws + ((size_t)32 << 20));
    bf16_t* ctx    = (bf16_t*)(ws + ((size_t)40 << 20));

    // K0a: x -> bf16 (4096*1024 elems, 8/thread)
    cvt_x_kernel<<<2048, 256, 0, stream>>>(x, x_bf);
    // K0b: weight transposes ([K][N] fp32 -> [N][K] bf16)
    transpose_cvt_kernel<<<dim3(32, 32), dim3(32, 8), 0, stream>>>(Wq, Wqkv_t, 1024, 1024);
    transpose_cvt_kernel<<<dim3(32, 32), dim3(32, 8), 0, stream>>>(Wk, Wqkv_t + (size_t)1024 * 1024, 1024, 1024);
    transpose_cvt_kernel<<<dim3(32, 32), dim3(32, 8), 0, stream>>>(Wv, Wqkv_t + (size_t)2048 * 1024, 1024, 1024);
    transpose_cvt_kernel<<<dim3(32, 32), dim3(32, 8), 0, stream>>>(Wo, Wo_t, 1024, 1024);
    // K1: QKV projection (M=4096, N=3072, K=1024)
    gemm_qkv_kernel<<<32 * 24, 256, 0, stream>>>(x_bf, Wqkv_t, Qb, Kb, Vt);
    // K2: causal attention (2*16 heads * 32 q-tiles), XCD-aware remap inside
    attn_kernel<<<B_SZ * NH * 32, 256, 0, stream>>>(Qb, Kb, Vt, ctx);
    // K3: output projection (M=4096, N=1024, K=1024)
    gemm_out_kernel<<<32 * 8, 256, 0, stream>>>(ctx, Wo_t, bo, out);
}

// Round 10
// 194.729 us; speedup vs baseline: 1.2478x; 1.1137x over previous
//
#include <hip/hip_runtime.h>
#include <hip/hip_bf16.h>
#include <cstdint>
#include <cstddef>

// ---------------------------------------------------------------------------
// MHA forward, MI355X (gfx950).  Pipeline:
//   K0a: x fp32 -> bf16
//   K0b: Wq/Wk/Wv/Wo fp32 -> bf16 TRANSPOSED
//   K1 : QKV GEMM; epilogue: Q (pre-scaled, log2 units), K, V^T scatter
//   K2 : causal flash attention -> ctx bf16
//        R7: SWAPPED QK^T (mfma(K,Q)) -> lane owns its q-row's scores ->
//        softmax reduce = in-reg + 2 shfl (was 32 shfl/iter, DS-pipe bound).
//        K/V LDS dbuf+prefetch (XOR swizzle), defer-max, XCD remap.
//   K3 : out = ctx @ Wo + bo
// ---------------------------------------------------------------------------

typedef __bf16 bf16_t;
typedef __bf16 bf16x2 __attribute__((ext_vector_type(2)));
typedef __bf16 bf16x8 __attribute__((ext_vector_type(8)));
typedef float  f32x4  __attribute__((ext_vector_type(4)));

#define B_SZ 2
#define T_SZ 2048
#define DIN  1024
#define NH   16
#define HD   64

// log2(e)/sqrt(HD): folded into Q at QKV-epilogue time.
#define SCL_Q (0.125f * 1.44269504088896f)

__device__ __forceinline__ void gld_lds16(const void* g, void* l) {
    __builtin_amdgcn_global_load_lds(
        (const __attribute__((address_space(1))) void*)g,
        (__attribute__((address_space(3))) void*)l,
        16, 0, 0);
}

// ---------------------------------------------------------------------------
__global__ __launch_bounds__(256) void cvt_x_kernel(const float* __restrict__ src,
                                                    bf16_t* __restrict__ dst) {
    int i = blockIdx.x * blockDim.x + threadIdx.x;
    size_t base = (size_t)i * 8;
    float4 a = *(const float4*)(src + base);
    float4 b = *(const float4*)(src + base + 4);
    bf16x8 v;
    v[0] = (bf16_t)a.x; v[1] = (bf16_t)a.y; v[2] = (bf16_t)a.z; v[3] = (bf16_t)a.w;
    v[4] = (bf16_t)b.x; v[5] = (bf16_t)b.y; v[6] = (bf16_t)b.z; v[7] = (bf16_t)b.w;
    *(bf16x8*)(dst + base) = v;
}

// ---------------------------------------------------------------------------
__global__ __launch_bounds__(256) void transpose_cvt_kernel(const float* __restrict__ src,
                                                            bf16_t* __restrict__ dst,
                                                            int R, int C) {
    __shared__ float tile[32][33];
    int c0 = blockIdx.x * 32, r0 = blockIdx.y * 32;
    int tx = threadIdx.x, ty = threadIdx.y;           // 32 x 8
#pragma unroll
    for (int i = 0; i < 32; i += 8)
        tile[ty + i][tx] = src[(size_t)(r0 + ty + i) * C + c0 + tx];
    __syncthreads();
#pragma unroll
    for (int i = 0; i < 32; i += 8)
        dst[(size_t)(c0 + ty + i) * R + r0 + tx] = (bf16_t)tile[tx][ty + i];
}

// ---------------------------------------------------------------------------
// Shared GEMM tile body (m97 structure)
// ---------------------------------------------------------------------------
__device__ __forceinline__ void gemm_tile_body(const bf16_t* __restrict__ A,
                                               const bf16_t* __restrict__ Bt,
                                               int m0, int n0, int K,
                                               f32x4 acc[4][4],
                                               bf16_t* As, bf16_t* Bs) {
    const int tid  = threadIdx.x;
    const int lane = tid & 63;
    const int wave = tid >> 6;
    const int wr   = (wave >> 1) * 64;
    const int wc   = (wave & 1) * 64;

#pragma unroll
    for (int mi = 0; mi < 4; ++mi)
#pragma unroll
        for (int ni = 0; ni < 4; ++ni)
            acc[mi][ni] = (f32x4){0.f, 0.f, 0.f, 0.f};

    for (int k0 = 0; k0 < K; k0 += 32) {
#pragma unroll
        for (int c = 0; c < 2; ++c) {
            int fb = (wave * 2 + c) * 1024;
            int e  = (fb >> 1) + lane * 8;
            int r  = e >> 5;
            int kk = e & 31;
            gld_lds16(A  + (size_t)(m0 + r) * K + k0 + kk, (char*)As + fb);
            gld_lds16(Bt + (size_t)(n0 + r) * K + k0 + kk, (char*)Bs + fb);
        }
        __syncthreads();

        bf16x8 af[4], bfr[4];
#pragma unroll
        for (int mi = 0; mi < 4; ++mi)
            af[mi] = *(const bf16x8*)(As + (wr + mi * 16 + (lane & 15)) * 32 + ((lane >> 4) * 8));
#pragma unroll
        for (int ni = 0; ni < 4; ++ni)
            bfr[ni] = *(const bf16x8*)(Bs + (wc + ni * 16 + (lane & 15)) * 32 + ((lane >> 4) * 8));
#pragma unroll
        for (int mi = 0; mi < 4; ++mi)
#pragma unroll
            for (int ni = 0; ni < 4; ++ni)
                acc[mi][ni] = __builtin_amdgcn_mfma_f32_16x16x32_bf16(af[mi], bfr[ni], acc[mi][ni], 0, 0, 0);
        __syncthreads();
    }
}

// ---------------------------------------------------------------------------
// K1: QKV projection + scatter (Q pre-scaled).
// ---------------------------------------------------------------------------
__global__ __launch_bounds__(256, 2) void gemm_qkv_kernel(const bf16_t* __restrict__ A,
                                                          const bf16_t* __restrict__ Bt,
                                                          bf16_t* __restrict__ Qb,
                                                          bf16_t* __restrict__ Kb,
                                                          bf16_t* __restrict__ Vt) {
    __shared__ alignas(16) bf16_t As[128 * 32];
    __shared__ alignas(16) bf16_t Bs[128 * 32];
    const int nTn = 3072 / 128;   // 24
    int m0 = (blockIdx.x / nTn) * 128;
    int n0 = (blockIdx.x % nTn) * 128;
    f32x4 acc[4][4];
    gemm_tile_body(A, Bt, m0, n0, DIN, acc, As, Bs);

    const int lane = threadIdx.x & 63;
    const int wave = threadIdx.x >> 6;
    const int wr = (wave >> 1) * 64, wc = (wave & 1) * 64;
#pragma unroll
    for (int mi = 0; mi < 4; ++mi)
#pragma unroll
        for (int ni = 0; ni < 4; ++ni)
#pragma unroll
            for (int j = 0; j < 4; ++j) {
                int m = m0 + wr + mi * 16 + ((lane >> 4) * 4) + j;
                int n = n0 + wc + ni * 16 + (lane & 15);
                int b = m >> 11, t = m & 2047;
                int part = n >> 10, c = n & 1023;
                int h = c >> 6, d = c & 63;
                float av = acc[mi][ni][j];
                if (part == 0)
                    Qb[(((size_t)(b * NH + h) * T_SZ + t) << 6) + d] = (bf16_t)(av * SCL_Q);
                else if (part == 1)
                    Kb[(((size_t)(b * NH + h) * T_SZ + t) << 6) + d] = (bf16_t)av;
                else
                    Vt[((size_t)(b * NH + h) * HD + d) * T_SZ + t] = (bf16_t)av;
            }
}

// ---------------------------------------------------------------------------
// K2: causal flash attention, swapped-QK^T in-register softmax.
// Lane (rgrp=lane>>4, rcol=lane&15) owns q-row (q0+rcol)'s scores:
// S[k0+ni*16+rgrp*4+j][q0+rcol] in s_acc[ni][j]  (mfma(K,Q) layout).
// Row stats mrun/lrun per-lane scalars; reduce = in-reg + shfl_xor(16,32).
// ---------------------------------------------------------------------------
__global__ __launch_bounds__(256, 3) void attn_kernel(const bf16_t* __restrict__ Qb,
                                                      const bf16_t* __restrict__ Kb,
                                                      const bf16_t* __restrict__ Vt,
                                                      bf16_t* __restrict__ ctx) {
    __shared__ alignas(16) bf16_t Ks[2][64 * 64];
    __shared__ alignas(16) bf16_t Vs[2][64 * 64];     // rows are d, cols are k
    __shared__ alignas(16) bf16_t P_lds[4][16][72];   // [wave][q-row][k], +8 pad

    const int raw = blockIdx.x;         // 0..1023
    const int xcd = raw & 7;
    const int jj  = raw >> 3;
    const int bh  = xcd * 4 + (jj & 3); // 4 heads per XCD -> 2MB K/V in L2
    const int qt  = 31 - (jj >> 2);     // big tiles dispatch first

    const int lane = threadIdx.x & 63;
    const int wave = threadIdx.x >> 6;

    const bf16_t* Qp = Qb + (size_t)bh * T_SZ * HD;
    const bf16_t* Kp = Kb + (size_t)bh * T_SZ * HD;
    const bf16_t* Vp = Vt + (size_t)bh * HD * T_SZ;

    const int q0 = qt * 64 + wave * 16;
    const int rgrp = lane >> 4;              // 0..3
    const int rcol = lane & 15;              // 0..15

    const int st_r  = (lane >> 3);
    const int st_sl = lane & 7;

    // Q fragments (A/B-operand layout: row=lane&15, k=rgrp*8+i per 32-chunk)
    bf16x8 qa[2];
#pragma unroll
    for (int s = 0; s < 2; ++s)
        qa[s] = *(const bf16x8*)(Qp + (size_t)(q0 + rcol) * HD + s * 32 + rgrp * 8);

    f32x4 o[4];                              // o[di][j] = O[q0+rgrp*4+j][di*16+rcol]
#pragma unroll
    for (int di = 0; di < 4; ++di) o[di] = (f32x4){0.f, 0.f, 0.f, 0.f};
    float mrun = -__builtin_inff();          // per-lane: row q0+rcol
    float lrun = 0.f;

#define STAGE(BUF, KT)                                                          \
    {                                                                           \
        const int k0s = (KT) * 64;                                              \
        _Pragma("unroll")                                                       \
        for (int c = 0; c < 2; ++c) {                                           \
            int r0 = (wave * 2 + c) * 8;                                        \
            int r  = r0 + st_r;                                                 \
            int sl = st_sl ^ (r & 7);                                           \
            gld_lds16(Kp + (size_t)(k0s + r) * HD + sl * 8,                     \
                      (char*)&Ks[BUF][0] + r0 * 128);                           \
            gld_lds16(Vp + (size_t)r * T_SZ + k0s + sl * 8,                     \
                      (char*)&Vs[BUF][0] + r0 * 128);                           \
        }                                                                       \
    }

    STAGE(0, 0);
    __syncthreads();
    int buf = 0;

    for (int kt = 0; kt <= qt; ++kt) {
        if (kt < qt) STAGE(buf ^ 1, kt + 1);

        const char* Kb_l = (const char*)&Ks[buf][0];
        const char* Vb_l = (const char*)&Vs[buf][0];

        // ---- S^T = K Q^T  (swapped operands; frag loads identical) ----
        f32x4 s_acc[4];
#pragma unroll
        for (int ni = 0; ni < 4; ++ni) s_acc[ni] = (f32x4){0.f, 0.f, 0.f, 0.f};
#pragma unroll
        for (int s = 0; s < 2; ++s)
#pragma unroll
            for (int ni = 0; ni < 4; ++ni) {
                int fr = ni * 16 + rcol;
                bf16x8 kb = *(const bf16x8*)(Kb_l + fr * 128 + (((s * 4 + rgrp) ^ (fr & 7)) << 4));
                s_acc[ni] = __builtin_amdgcn_mfma_f32_16x16x32_bf16(kb, qa[s], s_acc[ni], 0, 0, 0);
            }

        // ---- V fragments early (independent of softmax; fills DS slots) ----
        bf16x8 vf[2][4];
#pragma unroll
        for (int s = 0; s < 2; ++s)
#pragma unroll
            for (int di = 0; di < 4; ++di) {
                int fv = di * 16 + rcol;
                vf[s][di] = *(const bf16x8*)(Vb_l + fv * 128 + (((s * 4 + rgrp) ^ (fv & 7)) << 4));
            }

        // ---- mask + in-register row max ----
        float ptile[4][4];
        float pmax = -__builtin_inff();
        if (kt == qt) {                      // diagonal tile: causal mask
            const int qabs = q0 + rcol;
#pragma unroll
            for (int ni = 0; ni < 4; ++ni)
#pragma unroll
                for (int j = 0; j < 4; ++j) {
                    int kidx = qt * 64 + ni * 16 + rgrp * 4 + j;
                    float v = s_acc[ni][j];
                    if (kidx > qabs) v = -__builtin_inff();
                    ptile[ni][j] = v;
                    pmax = fmaxf(pmax, v);
                }
        } else {
#pragma unroll
            for (int ni = 0; ni < 4; ++ni)
#pragma unroll
                for (int j = 0; j < 4; ++j) {
                    float v = s_acc[ni][j];
                    ptile[ni][j] = v;
                    pmax = fmaxf(pmax, v);
                }
        }
        pmax = fmaxf(pmax, __shfl_xor(pmax, 16));
        pmax = fmaxf(pmax, __shfl_xor(pmax, 32));

        // ---- defer-max (THR=8, log2 units) ----
        const bool fullb = __any(pmax > mrun + 8.f);
        float a_self = 1.f;
        if (fullb) {
            float newm = fmaxf(mrun, pmax);
            a_self = exp2f(mrun - newm);     // exp2(-inf)=0 on first tile
            mrun = newm;
        }
        float rsum = 0.f;
#pragma unroll
        for (int ni = 0; ni < 4; ++ni)
#pragma unroll
            for (int j = 0; j < 4; ++j) {
                float p = exp2f(ptile[ni][j] - mrun);   // masked -> 0
                ptile[ni][j] = p;
                rsum += p;
            }
        rsum += __shfl_xor(rsum, 16);
        rsum += __shfl_xor(rsum, 32);
        if (fullb) {
            lrun = lrun * a_self + rsum;
            // rescale O: alpha for o-row rgrp*4+j lives on lane (rgrp*16 | row)
#pragma unroll
            for (int j = 0; j < 4; ++j) {
                float aj = __shfl(a_self, (lane & 48) | (rgrp * 4 + j));
#pragma unroll
                for (int di = 0; di < 4; ++di) o[di][j] *= aj;
            }
        } else {
            lrun += rsum;
        }

        // ---- P -> LDS row-major [q=rcol][k], packed b32 writes ----
#pragma unroll
        for (int ni = 0; ni < 4; ++ni)
#pragma unroll
            for (int jp = 0; jp < 2; ++jp) {
                bf16x2 pk;
                pk[0] = (bf16_t)ptile[ni][2 * jp];
                pk[1] = (bf16_t)ptile[ni][2 * jp + 1];
                *(bf16x2*)&P_lds[wave][rcol][ni * 16 + rgrp * 4 + 2 * jp] = pk;
            }
        // ---- O += P V  (P A-frag: row=rcol; V already in regs) ----
#pragma unroll
        for (int s = 0; s < 2; ++s) {
            bf16x8 pa = *(const bf16x8*)(&P_lds[wave][rcol][s * 32 + rgrp * 8]);
#pragma unroll
            for (int di = 0; di < 4; ++di)
                o[di] = __builtin_amdgcn_mfma_f32_16x16x32_bf16(pa, vf[s][di], o[di], 0, 0, 0);
        }
        __syncthreads();   // prefetch landed (vmcnt) + all waves done with buf
        buf ^= 1;
    }
#undef STAGE

    // ---- epilogue: ctx[b, t, h*64+d] = o / l  (l fetched per o-row) ----
    const int b = bh >> 4, h = bh & 15;
    float invl[4];
#pragma unroll
    for (int j = 0; j < 4; ++j) {
        float lj = __shfl(lrun, (lane & 48) | (rgrp * 4 + j));
        invl[j] = 1.f / lj;
    }
#pragma unroll
    for (int di = 0; di < 4; ++di)
#pragma unroll
        for (int j = 0; j < 4; ++j) {
            int q = q0 + rgrp * 4 + j;
            int d = di * 16 + rcol;
            ctx[((size_t)(b * T_SZ + q) * NH + h) * HD + d] = (bf16_t)(o[di][j] * invl[j]);
        }
}

// ---------------------------------------------------------------------------
// K3: out = ctx @ Wo + bo   (fp32 output)
// ---------------------------------------------------------------------------
__global__ __launch_bounds__(256, 2) void gemm_out_kernel(const bf16_t* __restrict__ A,
                                                          const bf16_t* __restrict__ Bt,
                                                          const float* __restrict__ bias,
                                                          float* __restrict__ out) {
    __shared__ alignas(16) bf16_t As[128 * 32];
    __shared__ alignas(16) bf16_t Bs[128 * 32];
    const int nTn = 1024 / 128;   // 8
    int m0 = (blockIdx.x / nTn) * 128;
    int n0 = (blockIdx.x % nTn) * 128;
    f32x4 acc[4][4];
    gemm_tile_body(A, Bt, m0, n0, DIN, acc, As, Bs);

    const int lane = threadIdx.x & 63;
    const int wave = threadIdx.x >> 6;
    const int wr = (wave >> 1) * 64, wc = (wave & 1) * 64;
#pragma unroll
    for (int mi = 0; mi < 4; ++mi)
#pragma unroll
        for (int ni = 0; ni < 4; ++ni) {
            int n = n0 + wc + ni * 16 + (lane & 15);
            float bv = bias[n];
#pragma unroll
            for (int j = 0; j < 4; ++j) {
                int m = m0 + wr + mi * 16 + ((lane >> 4) * 4) + j;
                out[(size_t)m * 1024 + n] = acc[mi][ni][j] + bv;
            }
        }
}

// ---------------------------------------------------------------------------
// Launch.  Workspace layout (48 MB total).
// ---------------------------------------------------------------------------
extern "C" void kernel_launch(void* const* d_in, const int* in_sizes, int n_in,
                              void* d_out, int out_size, void* d_ws, size_t ws_size,
                              hipStream_t stream) {
    const float* x  = (const float*)d_in[0];
    const float* Wq = (const float*)d_in[1];
    const float* Wk = (const float*)d_in[2];
    const float* Wv = (const float*)d_in[3];
    const float* Wo = (const float*)d_in[4];
    const float* bo = (const float*)d_in[5];
    float* out = (float*)d_out;

    char* ws = (char*)d_ws;
    bf16_t* x_bf   = (bf16_t*)(ws);
    bf16_t* Wqkv_t = (bf16_t*)(ws + ((size_t)8 << 20));
    bf16_t* Wo_t   = (bf16_t*)(ws + ((size_t)14 << 20));
    bf16_t* Qb     = (bf16_t*)(ws + ((size_t)16 << 20));
    bf16_t* Kb     = (bf16_t*)(ws + ((size_t)24 << 20));
    bf16_t* Vt     = (bf16_t*)(ws + ((size_t)32 << 20));
    bf16_t* ctx    = (bf16_t*)(ws + ((size_t)40 << 20));

    cvt_x_kernel<<<2048, 256, 0, stream>>>(x, x_bf);
    transpose_cvt_kernel<<<dim3(32, 32), dim3(32, 8), 0, stream>>>(Wq, Wqkv_t, 1024, 1024);
    transpose_cvt_kernel<<<dim3(32, 32), dim3(32, 8), 0, stream>>>(Wk, Wqkv_t + (size_t)1024 * 1024, 1024, 1024);
    transpose_cvt_kernel<<<dim3(32, 32), dim3(32, 8), 0, stream>>>(Wv, Wqkv_t + (size_t)2048 * 1024, 1024, 1024);
    transpose_cvt_kernel<<<dim3(32, 32), dim3(32, 8), 0, stream>>>(Wo, Wo_t, 1024, 1024);
    gemm_qkv_kernel<<<32 * 24, 256, 0, stream>>>(x_bf, Wqkv_t, Qb, Kb, Vt);
    attn_kernel<<<B_SZ * NH * 32, 256, 0, stream>>>(Qb, Kb, Vt, ctx);
    gemm_out_kernel<<<32 * 8, 256, 0, stream>>>(ctx, Wo_t, bo, out);
}

// Round 11
// 174.892 us; speedup vs baseline: 1.3893x; 1.1134x over previous
//
#include <hip/hip_runtime.h>
#include <hip/hip_bf16.h>
#include <cstdint>
#include <cstddef>

// ---------------------------------------------------------------------------
// MHA forward, MI355X (gfx950).  Pipeline:
//   K0 : prep = {x fp32->bf16} + {4x weight transpose+cast} fused, 1 launch
//   K1 : QKV GEMM (128x128, m97 structure, XCD-swizzled grid); epilogue
//        scatters Q (pre-scaled log2e/sqrt(d)), K -> [b,h,t,d]; V^T packed
//        bf16x4 stores -> [b,h,d,t]
//   K2 : causal flash attention (swapped QK^T, in-reg softmax, K/V LDS
//        dbuf+prefetch XOR-swizzled, defer-max, XCD remap)  [unchanged R10]
//   K3 : out = ctx @ Wo + bo  (64x128 tile, 512 blocks = 2/CU, XCD-swizzled)
// ---------------------------------------------------------------------------

typedef __bf16 bf16_t;
typedef __bf16 bf16x2 __attribute__((ext_vector_type(2)));
typedef __bf16 bf16x4 __attribute__((ext_vector_type(4)));
typedef __bf16 bf16x8 __attribute__((ext_vector_type(8)));
typedef float  f32x4  __attribute__((ext_vector_type(4)));

#define B_SZ 2
#define T_SZ 2048
#define DIN  1024
#define NH   16
#define HD   64

// log2(e)/sqrt(HD): folded into Q at QKV-epilogue time.
#define SCL_Q (0.125f * 1.44269504088896f)

__device__ __forceinline__ void gld_lds16(const void* g, void* l) {
    __builtin_amdgcn_global_load_lds(
        (const __attribute__((address_space(1))) void*)g,
        (__attribute__((address_space(3))) void*)l,
        16, 0, 0);
}

// ---------------------------------------------------------------------------
// K0: fused prep.  Blocks [0,2048): x fp32->bf16 (8 elems/thread).
// Blocks [2048,6144): 32x32 transpose+cast tiles of Wq/Wk/Wv/Wo.
// ---------------------------------------------------------------------------
__global__ __launch_bounds__(256) void prep_kernel(const float* __restrict__ x,
                                                   bf16_t* __restrict__ x_bf,
                                                   const float* __restrict__ Wq,
                                                   const float* __restrict__ Wk,
                                                   const float* __restrict__ Wv,
                                                   const float* __restrict__ Wo,
                                                   bf16_t* __restrict__ Wqkv_t,
                                                   bf16_t* __restrict__ Wo_t) {
    __shared__ float tile[32][33];
    const int bid = blockIdx.x;
    const int tid = threadIdx.x;
    if (bid < 2048) {
        size_t base = ((size_t)bid * 256 + tid) * 8;
        float4 a = *(const float4*)(x + base);
        float4 b = *(const float4*)(x + base + 4);
        bf16x8 v;
        v[0] = (bf16_t)a.x; v[1] = (bf16_t)a.y; v[2] = (bf16_t)a.z; v[3] = (bf16_t)a.w;
        v[4] = (bf16_t)b.x; v[5] = (bf16_t)b.y; v[6] = (bf16_t)b.z; v[7] = (bf16_t)b.w;
        *(bf16x8*)(x_bf + base) = v;
        return;
    }
    const int tb = bid - 2048;          // 0..4095
    const int w  = tb >> 10;            // weight id 0..3
    const int t2 = tb & 1023;
    const int c0 = (t2 & 31) * 32, r0 = (t2 >> 5) * 32;
    const float* src = (w == 0) ? Wq : (w == 1) ? Wk : (w == 2) ? Wv : Wo;
    bf16_t* dst = (w < 3) ? (Wqkv_t + (size_t)w * 1024 * 1024) : Wo_t;
    const int tx = tid & 31, ty = tid >> 5;   // 32 x 8
#pragma unroll
    for (int i = 0; i < 32; i += 8)
        tile[ty + i][tx] = src[(size_t)(r0 + ty + i) * 1024 + c0 + tx];
    __syncthreads();
#pragma unroll
    for (int i = 0; i < 32; i += 8)
        dst[(size_t)(c0 + ty + i) * 1024 + r0 + tx] = (bf16_t)tile[tx][ty + i];
}

// ---------------------------------------------------------------------------
// Shared GEMM tile body (m97 structure, 128x128)
// ---------------------------------------------------------------------------
__device__ __forceinline__ void gemm_tile_body(const bf16_t* __restrict__ A,
                                               const bf16_t* __restrict__ Bt,
                                               int m0, int n0, int K,
                                               f32x4 acc[4][4],
                                               bf16_t* As, bf16_t* Bs) {
    const int tid  = threadIdx.x;
    const int lane = tid & 63;
    const int wave = tid >> 6;
    const int wr   = (wave >> 1) * 64;
    const int wc   = (wave & 1) * 64;

#pragma unroll
    for (int mi = 0; mi < 4; ++mi)
#pragma unroll
        for (int ni = 0; ni < 4; ++ni)
            acc[mi][ni] = (f32x4){0.f, 0.f, 0.f, 0.f};

    for (int k0 = 0; k0 < K; k0 += 32) {
#pragma unroll
        for (int c = 0; c < 2; ++c) {
            int fb = (wave * 2 + c) * 1024;
            int e  = (fb >> 1) + lane * 8;
            int r  = e >> 5;
            int kk = e & 31;
            gld_lds16(A  + (size_t)(m0 + r) * K + k0 + kk, (char*)As + fb);
            gld_lds16(Bt + (size_t)(n0 + r) * K + k0 + kk, (char*)Bs + fb);
        }
        __syncthreads();

        bf16x8 af[4], bfr[4];
#pragma unroll
        for (int mi = 0; mi < 4; ++mi)
            af[mi] = *(const bf16x8*)(As + (wr + mi * 16 + (lane & 15)) * 32 + ((lane >> 4) * 8));
#pragma unroll
        for (int ni = 0; ni < 4; ++ni)
            bfr[ni] = *(const bf16x8*)(Bs + (wc + ni * 16 + (lane & 15)) * 32 + ((lane >> 4) * 8));
#pragma unroll
        for (int mi = 0; mi < 4; ++mi)
#pragma unroll
            for (int ni = 0; ni < 4; ++ni)
                acc[mi][ni] = __builtin_amdgcn_mfma_f32_16x16x32_bf16(af[mi], bfr[ni], acc[mi][ni], 0, 0, 0);
        __syncthreads();
    }
}

// ---------------------------------------------------------------------------
// K1: QKV projection + scatter (Q pre-scaled; V^T packed bf16x4 stores).
// Grid XCD-swizzled: 768 = 8 XCD x 96 contiguous tiles.
// ---------------------------------------------------------------------------
__global__ __launch_bounds__(256, 2) void gemm_qkv_kernel(const bf16_t* __restrict__ A,
                                                          const bf16_t* __restrict__ Bt,
                                                          bf16_t* __restrict__ Qb,
                                                          bf16_t* __restrict__ Kb,
                                                          bf16_t* __restrict__ Vt) {
    __shared__ alignas(16) bf16_t As[128 * 32];
    __shared__ alignas(16) bf16_t Bs[128 * 32];
    const int nTn = 3072 / 128;   // 24
    const int bid = (blockIdx.x & 7) * 96 + (blockIdx.x >> 3);   // XCD swizzle
    int m0 = (bid / nTn) * 128;
    int n0 = (bid % nTn) * 128;
    f32x4 acc[4][4];
    gemm_tile_body(A, Bt, m0, n0, DIN, acc, As, Bs);

    const int lane = threadIdx.x & 63;
    const int wave = threadIdx.x >> 6;
    const int wr = (wave >> 1) * 64, wc = (wave & 1) * 64;
#pragma unroll
    for (int mi = 0; mi < 4; ++mi)
#pragma unroll
        for (int ni = 0; ni < 4; ++ni) {
            int t0 = m0 + wr + mi * 16 + ((lane >> 4) * 4);   // 4-aligned
            int n  = n0 + wc + ni * 16 + (lane & 15);
            int b  = t0 >> 11, tl = t0 & 2047;
            int part = n >> 10, c = n & 1023;
            int h = c >> 6, d = c & 63;
            if (part == 2) {
                bf16x4 pv;
#pragma unroll
                for (int j = 0; j < 4; ++j) pv[j] = (bf16_t)acc[mi][ni][j];
                *(bf16x4*)&Vt[((size_t)(b * NH + h) * HD + d) * T_SZ + tl] = pv;
            } else if (part == 0) {
#pragma unroll
                for (int j = 0; j < 4; ++j)
                    Qb[(((size_t)(b * NH + h) * T_SZ + tl + j) << 6) + d] =
                        (bf16_t)(acc[mi][ni][j] * SCL_Q);
            } else {
#pragma unroll
                for (int j = 0; j < 4; ++j)
                    Kb[(((size_t)(b * NH + h) * T_SZ + tl + j) << 6) + d] =
                        (bf16_t)acc[mi][ni][j];
            }
        }
}

// ---------------------------------------------------------------------------
// K2: causal flash attention, swapped-QK^T in-register softmax. [R10 proven]
// ---------------------------------------------------------------------------
__global__ __launch_bounds__(256, 3) void attn_kernel(const bf16_t* __restrict__ Qb,
                                                      const bf16_t* __restrict__ Kb,
                                                      const bf16_t* __restrict__ Vt,
                                                      bf16_t* __restrict__ ctx) {
    __shared__ alignas(16) bf16_t Ks[2][64 * 64];
    __shared__ alignas(16) bf16_t Vs[2][64 * 64];     // rows are d, cols are k
    __shared__ alignas(16) bf16_t P_lds[4][16][72];   // [wave][q-row][k], +8 pad

    const int raw = blockIdx.x;         // 0..1023
    const int xcd = raw & 7;
    const int jj  = raw >> 3;
    const int bh  = xcd * 4 + (jj & 3); // 4 heads per XCD -> 2MB K/V in L2
    const int qt  = 31 - (jj >> 2);     // big tiles dispatch first

    const int lane = threadIdx.x & 63;
    const int wave = threadIdx.x >> 6;

    const bf16_t* Qp = Qb + (size_t)bh * T_SZ * HD;
    const bf16_t* Kp = Kb + (size_t)bh * T_SZ * HD;
    const bf16_t* Vp = Vt + (size_t)bh * HD * T_SZ;

    const int q0 = qt * 64 + wave * 16;
    const int rgrp = lane >> 4;              // 0..3
    const int rcol = lane & 15;              // 0..15

    const int st_r  = (lane >> 3);
    const int st_sl = lane & 7;

    bf16x8 qa[2];
#pragma unroll
    for (int s = 0; s < 2; ++s)
        qa[s] = *(const bf16x8*)(Qp + (size_t)(q0 + rcol) * HD + s * 32 + rgrp * 8);

    f32x4 o[4];
#pragma unroll
    for (int di = 0; di < 4; ++di) o[di] = (f32x4){0.f, 0.f, 0.f, 0.f};
    float mrun = -__builtin_inff();
    float lrun = 0.f;

#define STAGE(BUF, KT)                                                          \
    {                                                                           \
        const int k0s = (KT) * 64;                                              \
        _Pragma("unroll")                                                       \
        for (int c = 0; c < 2; ++c) {                                           \
            int r0 = (wave * 2 + c) * 8;                                        \
            int r  = r0 + st_r;                                                 \
            int sl = st_sl ^ (r & 7);                                           \
            gld_lds16(Kp + (size_t)(k0s + r) * HD + sl * 8,                     \
                      (char*)&Ks[BUF][0] + r0 * 128);                           \
            gld_lds16(Vp + (size_t)r * T_SZ + k0s + sl * 8,                     \
                      (char*)&Vs[BUF][0] + r0 * 128);                           \
        }                                                                       \
    }

    STAGE(0, 0);
    __syncthreads();
    int buf = 0;

    for (int kt = 0; kt <= qt; ++kt) {
        if (kt < qt) STAGE(buf ^ 1, kt + 1);

        const char* Kb_l = (const char*)&Ks[buf][0];
        const char* Vb_l = (const char*)&Vs[buf][0];

        f32x4 s_acc[4];
#pragma unroll
        for (int ni = 0; ni < 4; ++ni) s_acc[ni] = (f32x4){0.f, 0.f, 0.f, 0.f};
#pragma unroll
        for (int s = 0; s < 2; ++s)
#pragma unroll
            for (int ni = 0; ni < 4; ++ni) {
                int fr = ni * 16 + rcol;
                bf16x8 kb = *(const bf16x8*)(Kb_l + fr * 128 + (((s * 4 + rgrp) ^ (fr & 7)) << 4));
                s_acc[ni] = __builtin_amdgcn_mfma_f32_16x16x32_bf16(kb, qa[s], s_acc[ni], 0, 0, 0);
            }

        bf16x8 vf[2][4];
#pragma unroll
        for (int s = 0; s < 2; ++s)
#pragma unroll
            for (int di = 0; di < 4; ++di) {
                int fv = di * 16 + rcol;
                vf[s][di] = *(const bf16x8*)(Vb_l + fv * 128 + (((s * 4 + rgrp) ^ (fv & 7)) << 4));
            }

        float ptile[4][4];
        float pmax = -__builtin_inff();
        if (kt == qt) {
            const int qabs = q0 + rcol;
#pragma unroll
            for (int ni = 0; ni < 4; ++ni)
#pragma unroll
                for (int j = 0; j < 4; ++j) {
                    int kidx = qt * 64 + ni * 16 + rgrp * 4 + j;
                    float v = s_acc[ni][j];
                    if (kidx > qabs) v = -__builtin_inff();
                    ptile[ni][j] = v;
                    pmax = fmaxf(pmax, v);
                }
        } else {
#pragma unroll
            for (int ni = 0; ni < 4; ++ni)
#pragma unroll
                for (int j = 0; j < 4; ++j) {
                    float v = s_acc[ni][j];
                    ptile[ni][j] = v;
                    pmax = fmaxf(pmax, v);
                }
        }
        pmax = fmaxf(pmax, __shfl_xor(pmax, 16));
        pmax = fmaxf(pmax, __shfl_xor(pmax, 32));

        const bool fullb = __any(pmax > mrun + 8.f);
        float a_self = 1.f;
        if (fullb) {
            float newm = fmaxf(mrun, pmax);
            a_self = exp2f(mrun - newm);
            mrun = newm;
        }
        float rsum = 0.f;
#pragma unroll
        for (int ni = 0; ni < 4; ++ni)
#pragma unroll
            for (int j = 0; j < 4; ++j) {
                float p = exp2f(ptile[ni][j] - mrun);
                ptile[ni][j] = p;
                rsum += p;
            }
        rsum += __shfl_xor(rsum, 16);
        rsum += __shfl_xor(rsum, 32);
        if (fullb) {
            lrun = lrun * a_self + rsum;
#pragma unroll
            for (int j = 0; j < 4; ++j) {
                float aj = __shfl(a_self, (lane & 48) | (rgrp * 4 + j));
#pragma unroll
                for (int di = 0; di < 4; ++di) o[di][j] *= aj;
            }
        } else {
            lrun += rsum;
        }

#pragma unroll
        for (int ni = 0; ni < 4; ++ni)
#pragma unroll
            for (int jp = 0; jp < 2; ++jp) {
                bf16x2 pk;
                pk[0] = (bf16_t)ptile[ni][2 * jp];
                pk[1] = (bf16_t)ptile[ni][2 * jp + 1];
                *(bf16x2*)&P_lds[wave][rcol][ni * 16 + rgrp * 4 + 2 * jp] = pk;
            }
#pragma unroll
        for (int s = 0; s < 2; ++s) {
            bf16x8 pa = *(const bf16x8*)(&P_lds[wave][rcol][s * 32 + rgrp * 8]);
#pragma unroll
            for (int di = 0; di < 4; ++di)
                o[di] = __builtin_amdgcn_mfma_f32_16x16x32_bf16(pa, vf[s][di], o[di], 0, 0, 0);
        }
        __syncthreads();
        buf ^= 1;
    }
#undef STAGE

    const int b = bh >> 4, h = bh & 15;
    float invl[4];
#pragma unroll
    for (int j = 0; j < 4; ++j) {
        float lj = __shfl(lrun, (lane & 48) | (rgrp * 4 + j));
        invl[j] = 1.f / lj;
    }
#pragma unroll
    for (int di = 0; di < 4; ++di)
#pragma unroll
        for (int j = 0; j < 4; ++j) {
            int q = q0 + rgrp * 4 + j;
            int d = di * 16 + rcol;
            ctx[((size_t)(b * T_SZ + q) * NH + h) * HD + d] = (bf16_t)(o[di][j] * invl[j]);
        }
}

// ---------------------------------------------------------------------------
// K3: out = ctx @ Wo + bo.  64x128 tile, 4 waves 2x2 (32x64 each), 512
// blocks = 2/CU (was 256 = 1/CU, latency-starved).  XCD-swizzled grid.
// ---------------------------------------------------------------------------
__global__ __launch_bounds__(256, 3) void gemm_out_kernel(const bf16_t* __restrict__ A,
                                                          const bf16_t* __restrict__ Bt,
                                                          const float* __restrict__ bias,
                                                          float* __restrict__ out) {
    __shared__ alignas(16) bf16_t As[64 * 32];    // 4KB
    __shared__ alignas(16) bf16_t Bs[128 * 32];   // 8KB
    const int nTn = 1024 / 128;   // 8
    const int bid = (blockIdx.x & 7) * 64 + (blockIdx.x >> 3);   // XCD swizzle
    int m0 = (bid / nTn) * 64;
    int n0 = (bid % nTn) * 128;

    const int tid  = threadIdx.x;
    const int lane = tid & 63;
    const int wave = tid >> 6;
    const int wr   = (wave >> 1) * 32;   // 0 / 32
    const int wc   = (wave & 1) * 64;    // 0 / 64

    f32x4 acc[2][4];
#pragma unroll
    for (int mi = 0; mi < 2; ++mi)
#pragma unroll
        for (int ni = 0; ni < 4; ++ni)
            acc[mi][ni] = (f32x4){0.f, 0.f, 0.f, 0.f};

    for (int k0 = 0; k0 < DIN; k0 += 32) {
        // A-tile 64x32: 1 call/wave (1KB each).  B-tile 128x32: 2 calls/wave.
        {
            int fb = wave * 1024;
            int e  = (fb >> 1) + lane * 8;
            int r  = e >> 5;
            int kk = e & 31;
            gld_lds16(A + (size_t)(m0 + r) * DIN + k0 + kk, (char*)As + fb);
        }
#pragma unroll
        for (int c = 0; c < 2; ++c) {
            int fb = (wave * 2 + c) * 1024;
            int e  = (fb >> 1) + lane * 8;
            int r  = e >> 5;
            int kk = e & 31;
            gld_lds16(Bt + (size_t)(n0 + r) * DIN + k0 + kk, (char*)Bs + fb);
        }
        __syncthreads();

        bf16x8 af[2], bfr[4];
#pragma unroll
        for (int mi = 0; mi < 2; ++mi)
            af[mi] = *(const bf16x8*)(As + (wr + mi * 16 + (lane & 15)) * 32 + ((lane >> 4) * 8));
#pragma unroll
        for (int ni = 0; ni < 4; ++ni)
            bfr[ni] = *(const bf16x8*)(Bs + (wc + ni * 16 + (lane & 15)) * 32 + ((lane >> 4) * 8));
#pragma unroll
        for (int mi = 0; mi < 2; ++mi)
#pragma unroll
            for (int ni = 0; ni < 4; ++ni)
                acc[mi][ni] = __builtin_amdgcn_mfma_f32_16x16x32_bf16(af[mi], bfr[ni], acc[mi][ni], 0, 0, 0);
        __syncthreads();
    }

#pragma unroll
    for (int mi = 0; mi < 2; ++mi)
#pragma unroll
        for (int ni = 0; ni < 4; ++ni) {
            int n = n0 + wc + ni * 16 + (lane & 15);
            float bv = bias[n];
#pragma unroll
            for (int j = 0; j < 4; ++j) {
                int m = m0 + wr + mi * 16 + ((lane >> 4) * 4) + j;
                out[(size_t)m * 1024 + n] = acc[mi][ni][j] + bv;
            }
        }
}

// ---------------------------------------------------------------------------
// Launch.  Workspace layout (48 MB total).
// ---------------------------------------------------------------------------
extern "C" void kernel_launch(void* const* d_in, const int* in_sizes, int n_in,
                              void* d_out, int out_size, void* d_ws, size_t ws_size,
                              hipStream_t stream) {
    const float* x  = (const float*)d_in[0];
    const float* Wq = (const float*)d_in[1];
    const float* Wk = (const float*)d_in[2];
    const float* Wv = (const float*)d_in[3];
    const float* Wo = (const float*)d_in[4];
    const float* bo = (const float*)d_in[5];
    float* out = (float*)d_out;

    char* ws = (char*)d_ws;
    bf16_t* x_bf   = (bf16_t*)(ws);
    bf16_t* Wqkv_t = (bf16_t*)(ws + ((size_t)8 << 20));
    bf16_t* Wo_t   = (bf16_t*)(ws + ((size_t)14 << 20));
    bf16_t* Qb     = (bf16_t*)(ws + ((size_t)16 << 20));
    bf16_t* Kb     = (bf16_t*)(ws + ((size_t)24 << 20));
    bf16_t* Vt     = (bf16_t*)(ws + ((size_t)32 << 20));
    bf16_t* ctx    = (bf16_t*)(ws + ((size_t)40 << 20));

    // K0: fused cast + 4 weight transposes (1 launch, 6144 blocks)
    prep_kernel<<<6144, 256, 0, stream>>>(x, x_bf, Wq, Wk, Wv, Wo, Wqkv_t, Wo_t);
    // K1: QKV projection (M=4096, N=3072, K=1024), XCD-swizzled
    gemm_qkv_kernel<<<32 * 24, 256, 0, stream>>>(x_bf, Wqkv_t, Qb, Kb, Vt);
    // K2: causal attention (XCD remap inside)
    attn_kernel<<<B_SZ * NH * 32, 256, 0, stream>>>(Qb, Kb, Vt, ctx);
    // K3: output projection (M=4096, N=1024, K=1024), 64x128 tiles
    gemm_out_kernel<<<64 * 8, 256, 0, stream>>>(ctx, Wo_t, bo, out);
}